// Round 1
// baseline (690.609 us; speedup 1.0000x reference)
//
#include <hip/hip_runtime.h>

#define D 64

__device__ __forceinline__ float lane_bcast(float v, int k) {
    return __int_as_float(__builtin_amdgcn_readlane(__float_as_int(v), k));
}

// ---------------- CSR build ----------------

__global__ void count_kernel(const int* __restrict__ ei, int* __restrict__ cnt, int E) {
    int e = blockIdx.x * blockDim.x + threadIdx.x;
    if (e < E) atomicAdd(&cnt[ei[E + e]], 1);
}

__global__ void scan_kernel(const int* __restrict__ cnt, int* __restrict__ offsets,
                            int* __restrict__ cursor, int N, int E) {
    __shared__ int sdata[1024];
    int t = threadIdx.x;
    int chunk = (N + 1023) >> 10;
    int b0 = t * chunk;
    int b1 = b0 + chunk; if (b1 > N) b1 = N;
    if (b0 > N) b0 = N;
    int sum = 0;
    for (int i = b0; i < b1; ++i) sum += cnt[i];
    sdata[t] = sum;
    __syncthreads();
    for (int o = 1; o < 1024; o <<= 1) {
        int v = sdata[t];
        int u = (t >= o) ? sdata[t - o] : 0;
        __syncthreads();
        sdata[t] = v + u;
        __syncthreads();
    }
    int run = sdata[t] - sum;   // exclusive prefix of this thread's chunk
    for (int i = b0; i < b1; ++i) {
        int c = cnt[i];
        offsets[i] = run;
        cursor[i]  = run;
        run += c;
    }
    if (t == 0) offsets[N] = E;
}

__global__ void fill_kernel(const int* __restrict__ ei, int* __restrict__ cursor,
                            int* __restrict__ srclist, int E) {
    int e = blockIdx.x * blockDim.x + threadIdx.x;
    if (e < E) {
        int dst = ei[E + e];
        int pos = atomicAdd(&cursor[dst], 1);
        srclist[pos] = ei[e];
    }
}

// ---------------- mean aggregation (gather over CSR) ----------------
// one wave per node; lane = feature

__global__ void agg_kernel(const float* __restrict__ in, const int* __restrict__ offsets,
                           const int* __restrict__ srclist, float* __restrict__ agg, int N) {
    int lane = threadIdx.x & 63;
    int wid  = (blockIdx.x * blockDim.x + threadIdx.x) >> 6;
    int nw   = (gridDim.x * blockDim.x) >> 6;
    for (int i = wid; i < N; i += nw) {
        int beg = offsets[i], end = offsets[i + 1];
        float acc = 0.f;
        for (int base = beg; base < end; base += 64) {
            int m = end - base; if (m > 64) m = 64;
            int sl = (lane < m) ? srclist[base + lane] : 0;
            for (int e = 0; e < m; ++e) {
                int s = __builtin_amdgcn_readlane(sl, e);
                acc += in[(size_t)s * D + lane];
            }
        }
        int deg = end - beg;
        float scale = (deg > 0) ? 1.f / (float)deg : 0.f;
        agg[(size_t)i * D + lane] = acc * scale;
    }
}

// ---------------- combine: out = [relu](agg@Wl^T + bl + x@Wr^T) ----------------
// 4 waves/block, 4 nodes/wave-iteration; weights transposed in LDS;
// input-row broadcast via v_readlane (no LDS, no barrier in the hot loop).

__global__ void __launch_bounds__(256) combine_kernel(
    const float* __restrict__ agg, const float* __restrict__ x,
    const float* __restrict__ Wl, const float* __restrict__ bl,
    const float* __restrict__ Wr, float* __restrict__ out,
    int N, int relu) {
    __shared__ float wtl[D * D];
    __shared__ float wtr[D * D];
    int tid = threadIdx.x;
    for (int idx = tid; idx < D * D; idx += 256) {
        int f = idx >> 6, k = idx & 63;
        wtl[k * D + f] = Wl[idx];
        wtr[k * D + f] = Wr[idx];
    }
    __syncthreads();

    int lane  = tid & 63;
    int gwave = blockIdx.x * 4 + (tid >> 6);
    int nwaves = gridDim.x * 4;
    float bias = bl[lane];
    int ntiles = (N + 3) >> 2;

    for (int t = gwave; t < ntiles; t += nwaves) {
        int n0 = t * 4;
        bool v1 = (n0 + 1) < N, v2 = (n0 + 2) < N, v3 = (n0 + 3) < N;
        size_t r0 = (size_t)n0 * D + lane;
        float a0 = agg[r0];
        float x0 = x[r0];
        float a1 = v1 ? agg[r0 + D]     : 0.f;
        float x1 = v1 ? x[r0 + D]       : 0.f;
        float a2 = v2 ? agg[r0 + 2 * D] : 0.f;
        float x2 = v2 ? x[r0 + 2 * D]   : 0.f;
        float a3 = v3 ? agg[r0 + 3 * D] : 0.f;
        float x3 = v3 ? x[r0 + 3 * D]   : 0.f;

        float c0 = bias, c1 = bias, c2 = bias, c3 = bias;
#pragma unroll
        for (int k = 0; k < D; ++k) {
            float wl = wtl[k * D + lane];
            float wr = wtr[k * D + lane];
            c0 += lane_bcast(a0, k) * wl + lane_bcast(x0, k) * wr;
            c1 += lane_bcast(a1, k) * wl + lane_bcast(x1, k) * wr;
            c2 += lane_bcast(a2, k) * wl + lane_bcast(x2, k) * wr;
            c3 += lane_bcast(a3, k) * wl + lane_bcast(x3, k) * wr;
        }
        if (relu) {
            c0 = fmaxf(c0, 0.f); c1 = fmaxf(c1, 0.f);
            c2 = fmaxf(c2, 0.f); c3 = fmaxf(c3, 0.f);
        }
        out[r0] = c0;
        if (v1) out[r0 + D]     = c1;
        if (v2) out[r0 + 2 * D] = c2;
        if (v3) out[r0 + 3 * D] = c3;
    }
}

extern "C" void kernel_launch(void* const* d_in, const int* in_sizes, int n_in,
                              void* d_out, int out_size, void* d_ws, size_t ws_size,
                              hipStream_t stream) {
    const float* x   = (const float*)d_in[0];
    const int*   ei  = (const int*)d_in[1];
    const float* W1l = (const float*)d_in[2];
    const float* b1l = (const float*)d_in[3];
    const float* W1r = (const float*)d_in[4];
    const float* W2l = (const float*)d_in[5];
    const float* b2l = (const float*)d_in[6];
    const float* W2r = (const float*)d_in[7];
    float* out = (float*)d_out;

    int N = in_sizes[0] / D;   // 100000
    int E = in_sizes[1] / 2;   // 1000000

    char* ws = (char*)d_ws;
    float* agg    = (float*)ws;                                   // N*D floats
    int*   srclist = (int*)(ws + (size_t)N * D * 4);              // E ints
    int*   offsets = (int*)(ws + (size_t)N * D * 4 + (size_t)E * 4); // N+1 ints
    int*   cnt     = offsets + (N + 1);                           // N ints
    int*   cursor  = cnt + N;                                     // N ints

    hipMemsetAsync(cnt, 0, (size_t)N * 4, stream);

    int eblocks = (E + 255) / 256;
    count_kernel<<<eblocks, 256, 0, stream>>>(ei, cnt, E);
    scan_kernel<<<1, 1024, 0, stream>>>(cnt, offsets, cursor, N, E);
    fill_kernel<<<eblocks, 256, 0, stream>>>(ei, cursor, srclist, E);

    // layer 1: h (stored in d_out) = relu(mean_agg(x)@W1l^T + b1l + x@W1r^T)
    agg_kernel<<<2048, 256, 0, stream>>>(x, offsets, srclist, agg, N);
    combine_kernel<<<512, 256, 0, stream>>>(agg, x, W1l, b1l, W1r, out, N, 1);

    // layer 2: out = mean_agg(h)@W2l^T + b2l + h@W2r^T   (in-place safe per-row)
    agg_kernel<<<2048, 256, 0, stream>>>(out, offsets, srclist, agg, N);
    combine_kernel<<<512, 256, 0, stream>>>(agg, out, W2l, b2l, W2r, out, N, 0);
}

// Round 2
// 435.534 us; speedup vs baseline: 1.5857x; 1.5857x over previous
//
#include <hip/hip_runtime.h>

#define D 64

__device__ __forceinline__ float lane_bcast(float v, int k) {
    return __int_as_float(__builtin_amdgcn_readlane(__float_as_int(v), k));
}

// ---------------- CSR build (unordered segments -> no global scan) ----------------

__global__ void count_kernel(const int* __restrict__ ei, int* __restrict__ cnt, int E) {
    int e = blockIdx.x * blockDim.x + threadIdx.x;
    if (e < E) atomicAdd(&cnt[ei[E + e]], 1);
}

// Each node gets a contiguous slice of srclist, allocated by a wave-scanned
// atomic bump allocator. Segment order across nodes is arbitrary (CSR doesn't care).
__global__ void alloc_kernel(const int* __restrict__ cnt, int* __restrict__ beg,
                             int* __restrict__ cursor, int* __restrict__ total, int N) {
    int i = blockIdx.x * blockDim.x + threadIdx.x;
    int lane = threadIdx.x & 63;
    int c = (i < N) ? cnt[i] : 0;
    // wave inclusive scan
    int p = c;
#pragma unroll
    for (int o = 1; o < 64; o <<= 1) {
        int u = __shfl_up(p, o, 64);
        if (lane >= o) p += u;
    }
    int wavetot = __shfl(p, 63, 64);
    int base = 0;
    if (lane == 63) base = atomicAdd(total, wavetot);
    base = __shfl(base, 63, 64);
    int off = base + p - c;  // exclusive prefix within wave + global base
    if (i < N) { beg[i] = off; cursor[i] = off; }
}

__global__ void fill_kernel(const int* __restrict__ ei, int* __restrict__ cursor,
                            int* __restrict__ srclist, int E) {
    int e = blockIdx.x * blockDim.x + threadIdx.x;
    if (e < E) {
        int dst = ei[E + e];
        int pos = atomicAdd(&cursor[dst], 1);
        srclist[pos] = ei[e];
    }
}

// ---------------- mean aggregation (gather over CSR) ----------------
// one wave per node; 4 edges per iteration: quarter-wave q handles edge e+q,
// each lane reads float4 (16 lanes x 16B = one 256B row per quarter-wave).

__global__ void agg_kernel(const float* __restrict__ in, const int* __restrict__ beg_,
                           const int* __restrict__ cnt_, const int* __restrict__ srclist,
                           float* __restrict__ agg, int N) {
    int lane = threadIdx.x & 63;
    int sub  = lane >> 4;    // which of 4 edges this iteration
    int fl   = lane & 15;    // float4 index within the 64-float row
    int wid  = (blockIdx.x * blockDim.x + threadIdx.x) >> 6;
    int nw   = (gridDim.x * blockDim.x) >> 6;
    for (int i = wid; i < N; i += nw) {
        int beg = beg_[i], deg = cnt_[i];
        int end = beg + deg;
        float ax = 0.f, ay = 0.f, az = 0.f, aw = 0.f;
        for (int base = beg; base < end; base += 64) {
            int m = end - base; if (m > 64) m = 64;
            int sl = (lane < m) ? srclist[base + lane] : 0;
            for (int e = 0; e < m; e += 4) {
                int ee = e + sub;
                int si = __shfl(sl, (ee < 64) ? ee : 0, 64);
                if (ee < m) {
                    const float4 v = *((const float4*)(in + (size_t)si * D) + fl);
                    ax += v.x; ay += v.y; az += v.z; aw += v.w;
                }
            }
        }
        // reduce across the 4 quarter-wave groups
        ax += __shfl_xor(ax, 16, 64); ay += __shfl_xor(ay, 16, 64);
        az += __shfl_xor(az, 16, 64); aw += __shfl_xor(aw, 16, 64);
        ax += __shfl_xor(ax, 32, 64); ay += __shfl_xor(ay, 32, 64);
        az += __shfl_xor(az, 32, 64); aw += __shfl_xor(aw, 32, 64);
        float scale = (deg > 0) ? 1.f / (float)deg : 0.f;
        if (sub == 0) {
            float4 r; r.x = ax * scale; r.y = ay * scale; r.z = az * scale; r.w = aw * scale;
            *((float4*)(agg + (size_t)i * D) + fl) = r;
        }
    }
}

// ---------------- combine: out = [relu](agg@Wl^T + bl + x@Wr^T) ----------------

__global__ void __launch_bounds__(256) combine_kernel(
    const float* __restrict__ agg, const float* __restrict__ x,
    const float* __restrict__ Wl, const float* __restrict__ bl,
    const float* __restrict__ Wr, float* __restrict__ out,
    int N, int relu) {
    __shared__ float wtl[D * D];
    __shared__ float wtr[D * D];
    int tid = threadIdx.x;
    for (int idx = tid; idx < D * D; idx += 256) {
        int f = idx >> 6, k = idx & 63;
        wtl[k * D + f] = Wl[idx];
        wtr[k * D + f] = Wr[idx];
    }
    __syncthreads();

    int lane  = tid & 63;
    int gwave = blockIdx.x * 4 + (tid >> 6);
    int nwaves = gridDim.x * 4;
    float bias = bl[lane];
    int ntiles = (N + 3) >> 2;

    for (int t = gwave; t < ntiles; t += nwaves) {
        int n0 = t * 4;
        bool v1 = (n0 + 1) < N, v2 = (n0 + 2) < N, v3 = (n0 + 3) < N;
        size_t r0 = (size_t)n0 * D + lane;
        float a0 = agg[r0];
        float x0 = x[r0];
        float a1 = v1 ? agg[r0 + D]     : 0.f;
        float x1 = v1 ? x[r0 + D]       : 0.f;
        float a2 = v2 ? agg[r0 + 2 * D] : 0.f;
        float x2 = v2 ? x[r0 + 2 * D]   : 0.f;
        float a3 = v3 ? agg[r0 + 3 * D] : 0.f;
        float x3 = v3 ? x[r0 + 3 * D]   : 0.f;

        float c0 = bias, c1 = bias, c2 = bias, c3 = bias;
#pragma unroll
        for (int k = 0; k < D; ++k) {
            float wl = wtl[k * D + lane];
            float wr = wtr[k * D + lane];
            c0 += lane_bcast(a0, k) * wl + lane_bcast(x0, k) * wr;
            c1 += lane_bcast(a1, k) * wl + lane_bcast(x1, k) * wr;
            c2 += lane_bcast(a2, k) * wl + lane_bcast(x2, k) * wr;
            c3 += lane_bcast(a3, k) * wl + lane_bcast(x3, k) * wr;
        }
        if (relu) {
            c0 = fmaxf(c0, 0.f); c1 = fmaxf(c1, 0.f);
            c2 = fmaxf(c2, 0.f); c3 = fmaxf(c3, 0.f);
        }
        out[r0] = c0;
        if (v1) out[r0 + D]     = c1;
        if (v2) out[r0 + 2 * D] = c2;
        if (v3) out[r0 + 3 * D] = c3;
    }
}

extern "C" void kernel_launch(void* const* d_in, const int* in_sizes, int n_in,
                              void* d_out, int out_size, void* d_ws, size_t ws_size,
                              hipStream_t stream) {
    const float* x   = (const float*)d_in[0];
    const int*   ei  = (const int*)d_in[1];
    const float* W1l = (const float*)d_in[2];
    const float* b1l = (const float*)d_in[3];
    const float* W1r = (const float*)d_in[4];
    const float* W2l = (const float*)d_in[5];
    const float* b2l = (const float*)d_in[6];
    const float* W2r = (const float*)d_in[7];
    float* out = (float*)d_out;

    int N = in_sizes[0] / D;   // 100000
    int E = in_sizes[1] / 2;   // 1000000

    char* ws = (char*)d_ws;
    float* agg     = (float*)ws;                                     // N*D floats
    int*   srclist = (int*)(ws + (size_t)N * D * 4);                 // E ints
    int*   beg     = (int*)(ws + (size_t)N * D * 4 + (size_t)E * 4); // N ints
    int*   cursor  = beg + N;                                        // N ints
    int*   cnt     = cursor + N;                                     // N ints
    int*   total   = cnt + N;                                        // 1 int (adjacent to cnt)

    // zero cnt + total in one memset
    hipMemsetAsync(cnt, 0, (size_t)(N + 1) * 4, stream);

    int eblocks = (E + 255) / 256;
    int nblocks = (N + 255) / 256;
    count_kernel<<<eblocks, 256, 0, stream>>>(ei, cnt, E);
    alloc_kernel<<<nblocks, 256, 0, stream>>>(cnt, beg, cursor, total, N);
    fill_kernel<<<eblocks, 256, 0, stream>>>(ei, cursor, srclist, E);

    // layer 1: h (stored in d_out) = relu(mean_agg(x)@W1l^T + b1l + x@W1r^T)
    agg_kernel<<<2048, 256, 0, stream>>>(x, beg, cnt, srclist, agg, N);
    combine_kernel<<<512, 256, 0, stream>>>(agg, x, W1l, b1l, W1r, out, N, 1);

    // layer 2: out = mean_agg(h)@W2l^T + b2l + h@W2r^T   (in-place safe per-row)
    agg_kernel<<<2048, 256, 0, stream>>>(out, beg, cnt, srclist, agg, N);
    combine_kernel<<<512, 256, 0, stream>>>(agg, out, W2l, b2l, W2r, out, N, 0);
}